// Round 8
// baseline (173.491 us; speedup 1.0000x reference)
//
#include <hip/hip_runtime.h>
#include <hip/hip_cooperative_groups.h>

namespace cg = cooperative_groups;

#define N_IN   4096
#define N_NPB  64
#define COLS   16384
#define BATCH  128

typedef unsigned int       uint;
typedef unsigned short     ushort;
typedef unsigned char      uchar;
typedef unsigned long long u64;
typedef __attribute__((ext_vector_type(2))) _Float16 h2;

// ---------------------------------------------------------------------------
// ws layout:
//   [0,      1 MiB)       xTh  : f16 xT[4096][128] (ushort)
//   [1 MiB,  1 MiB+128 K) keep : u64 per column (byte b = keep bits k in [8b,8b+8))
// ---------------------------------------------------------------------------

static __device__ __forceinline__ ushort f16bits(float v) {
  return __builtin_bit_cast(ushort, (_Float16)v);
}

// ===========================================================================
// Fused cooperative kernel. Grid 512 x 512 threads = 2 blocks/CU (safe).
// Phase 1: transpose one 32x32 x-tile + keepmask for own 32 columns.
// grid.sync(). Phase 2: gather-accumulate 32 columns (8 waves x 4 cols).
// ===========================================================================
__global__ __launch_bounds__(512, 4) void fused_kernel(
    const float* __restrict__ x, const float* __restrict__ w,
    const int* __restrict__ idx, ushort* __restrict__ xTh,
    uchar* __restrict__ keep8, float* __restrict__ out) {
  __shared__ __align__(16) char smem[33280];

  const int bid = blockIdx.x;   // 0..511
  const int tid = threadIdx.x;  // 0..511
  const int c0  = bid * 32;     // this block's 32 columns

  // ---------------- Phase 1 ----------------
  {
    float (*tile)[33] = reinterpret_cast<float(*)[33]>(smem);        // 4224 B
    int   (*idxt)[33] = reinterpret_cast<int(*)[33]>(smem + 4224);   // 8448 B

    // 1a: load one 32x32 tile of x (features i0.., batches b0..)
    const int i0 = (bid & 127) * 32;
    const int b0 = (bid >> 7) * 32;
    const int tx = tid & 31;
    const int ty = tid >> 5;   // 0..15
    tile[ty][tx]      = x[(b0 + ty) * N_IN + i0 + tx];
    tile[ty + 16][tx] = x[(b0 + ty + 16) * N_IN + i0 + tx];

    // 1b: stage this block's idx tile [64 k][32 c] into LDS (coalesced)
    for (int e = tid; e < 64 * 32; e += 512) {
      const int k = e >> 5, c = e & 31;
      idxt[k][c] = idx[k * COLS + c0 + c];
    }
    __syncthreads();

    // 1c: write transposed f16 x
    xTh[(i0 + ty) * BATCH + b0 + tx]      = f16bits(tile[tx][ty]);
    xTh[(i0 + ty + 16) * BATCH + b0 + tx] = f16bits(tile[tx][ty + 16]);

    // 1d: keepmask. Waves 0..3, wave wv owns k-group [wv*16, wv*16+16);
    // lanes 0-31 handle j-bits [KB,KB+8) for cols 0..31, lanes 32-63 the
    // upper 8 bits. Each lane emits one byte of the column's 64-bit mask.
    if (tid < 256) {
      const int wv   = tid >> 6;        // wave-uniform k-group
      const int lane = tid & 63;
      const int c    = lane & 31;
      const int jh   = lane >> 5;       // 0: bits KB..KB+7, 1: KB+8..KB+15
      const int KB   = wv * 16;
      const int J0   = KB + jh * 8;

      int  g[8];
      uint m[8];
#pragma unroll
      for (int j = 0; j < 8; ++j) { g[j] = idxt[J0 + j][c]; m[j] = 0xffffffffu; }
      // pairs within own 8
#pragma unroll
      for (int j = 0; j < 8; ++j)
#pragma unroll
        for (int kp = j + 1; kp < 8; ++kp)
          m[j] = min(m[j], (uint)(g[j] ^ g[kp]));
      // lower half also compares against the adjacent 8 (KB+8..KB+15)
      if (jh == 0) {
#pragma unroll
        for (int q = 0; q < 8; ++q) {
          const int vk = idxt[KB + 8 + q][c];
#pragma unroll
          for (int j = 0; j < 8; ++j) m[j] = min(m[j], (uint)(g[j] ^ vk));
        }
      }
      // stream all k' >= KB+16 (valid comparators for both halves)
      for (int kp = KB + 16; kp < 64; ++kp) {
        const int vk = idxt[kp][c];
#pragma unroll
        for (int j = 0; j < 8; ++j) m[j] = min(m[j], (uint)(g[j] ^ vk));
      }
      uint bits = 0;
#pragma unroll
      for (int j = 0; j < 8; ++j) bits |= (m[j] != 0u) ? (1u << j) : 0u;
      keep8[(c0 + c) * 8 + wv * 2 + jh] = (uchar)bits;
    }
  }

  __threadfence();          // device-scope release of xTh/keep8
  cg::this_grid().sync();

  // ---------------- Phase 2: out[b,c] = sum_k wk * xTh[idx[k][c]][b] ------
  // 8 waves x 4 cols = 32 cols; per wave-quad g=lane>>4 (col), b8=lane&15
  // (batch octet: one dwordx4 = 8 f16 batches = full 256 B row / 16 lanes).
  u64   (*pk)[32]   = reinterpret_cast<u64(*)[32]>(smem);            // 16384 B
  float (*res)[132] = reinterpret_cast<float(*)[132]>(smem + 16384); // 16896 B
  const u64* keep = reinterpret_cast<const u64*>(keep8);

  __syncthreads();   // smem reuse guard

  // Stage packed (offset | dup'd f16 weight); 4 entries per thread, coalesced.
  {
    const int c  = tid & 31;
    const int k0 = tid >> 5;          // 0..15
    const u64 km = keep[c0 + c];
#pragma unroll
    for (int p = 0; p < 4; ++p) {
      const int k   = k0 + p * 16;
      const int row = idx[k * COLS + c0 + c];
      float wv      = w[k * COLS + c0 + c];
      wv = ((km >> k) & 1ull) ? wv : 0.0f;
      const uint hb = (uint)f16bits(wv);
      pk[k][c] = ((u64)((hb << 16) | hb) << 32) | ((u64)((uint)row << 8));
    }
  }
  __syncthreads();

  const int wave = tid >> 6;
  const int lane = tid & 63;
  const int g    = lane >> 4;
  const int b8   = lane & 15;
  const int cl   = wave * 4 + g;

  const char* xb = (const char*)xTh;
  const uint  bo = (uint)b8 * 16;

  h2 a0 = (h2)0.0f, a1 = (h2)0.0f, a2 = (h2)0.0f, a3 = (h2)0.0f;
#pragma unroll
  for (int k = 0; k < N_NPB; ++k) {
    const u64  e   = pk[k][cl];                  // ds_read_b64, broadcast
    const uint off = (uint)e + bo;               // one v_add_u32
    const h2   wh  = __builtin_bit_cast(h2, (uint)(e >> 32));
    const uint4 u  = *(const uint4*)(xb + off);  // 8 f16 batches
    a0 += __builtin_bit_cast(h2, u.x) * wh;      // v_pk_fma_f16
    a1 += __builtin_bit_cast(h2, u.y) * wh;
    a2 += __builtin_bit_cast(h2, u.z) * wh;
    a3 += __builtin_bit_cast(h2, u.w) * wh;
  }

  {
    float* r = &res[cl][b8 * 8];
    r[0] = (float)a0.x; r[1] = (float)a0.y;
    r[2] = (float)a1.x; r[3] = (float)a1.y;
    r[4] = (float)a2.x; r[5] = (float)a2.y;
    r[6] = (float)a3.x; r[7] = (float)a3.y;
  }
  __syncthreads();

  for (int e = tid; e < BATCH * 32; e += 512) {
    const int b = e >> 5, cc = e & 31;
    out[b * COLS + c0 + cc] = res[cc][b];
  }
}

// ===========================================================================
// Fallback path (round-6, known-good 23.8 us) in case cooperative launch
// is rejected on this harness.
// ===========================================================================
template <int KB>
static __device__ __forceinline__ uint bits_stream(const int* __restrict__ ip) {
  int  g[16];
  uint m[16];
#pragma unroll
  for (int j = 0; j < 16; ++j) { g[j] = ip[(KB + j) * COLS]; m[j] = 0xffffffffu; }
#pragma unroll
  for (int j = 0; j < 16; ++j)
#pragma unroll
    for (int kp = j + 1; kp < 16; ++kp)
      m[j] = min(m[j], (uint)(g[j] ^ g[kp]));
#pragma unroll 4
  for (int kp = KB + 16; kp < 64; ++kp) {
    const int vk = ip[kp * COLS];
#pragma unroll
    for (int j = 0; j < 16; ++j) m[j] = min(m[j], (uint)(g[j] ^ vk));
  }
  uint bits = 0;
#pragma unroll
  for (int j = 0; j < 16; ++j) bits |= (m[j] != 0u) ? (1u << j) : 0u;
  return bits;
}

__global__ __launch_bounds__(256, 4) void prep_kernel(
    const float* __restrict__ x, const int* __restrict__ idx,
    ushort* __restrict__ xTh, ushort* __restrict__ keep16) {
  const int bid = blockIdx.x;
  const int tid = threadIdx.x;
  if (bid < 512) {
    __shared__ float tile[32][33];
    const int i0 = (bid & 127) * 32;
    const int b0 = (bid >> 7) * 32;
    const int tx = tid & 31;
    const int ty = tid >> 5;
#pragma unroll
    for (int j = 0; j < 32; j += 8)
      tile[ty + j][tx] = x[(b0 + ty + j) * N_IN + i0 + tx];
    __syncthreads();
#pragma unroll
    for (int j = 0; j < 32; j += 8)
      xTh[(i0 + ty + j) * BATCH + b0 + tx] = f16bits(tile[tx][ty + j]);
  } else {
    const int kg = __builtin_amdgcn_readfirstlane(tid >> 6);
    const int c  = (bid - 512) * 64 + (tid & 63);
    const int* ip = idx + c;
    uint bits;
    if      (kg == 0) bits = bits_stream<0>(ip);
    else if (kg == 1) bits = bits_stream<16>(ip);
    else if (kg == 2) bits = bits_stream<32>(ip);
    else              bits = bits_stream<48>(ip);
    keep16[c * 4 + kg] = (ushort)bits;
  }
}

__global__ __launch_bounds__(512, 8) void branch_main_kernel(
    const float* __restrict__ w, const int* __restrict__ idx,
    const u64* __restrict__ keep, const ushort* __restrict__ xTh,
    float* __restrict__ out) {
  __shared__ u64   pk[N_NPB][16];
  __shared__ float res[2][16][132];

  const int tid = threadIdx.x;
  const int c0  = blockIdx.x * 16;

  {
    const int cl = tid & 15;
    const int k0 = (tid >> 4) * 2;
    const u64 km = keep[c0 + cl];
#pragma unroll
    for (int p = 0; p < 2; ++p) {
      const int k   = k0 + p;
      const int row = idx[k * COLS + c0 + cl];
      float wv      = w[k * COLS + c0 + cl];
      wv = ((km >> k) & 1ull) ? wv : 0.0f;
      const uint hb = (uint)f16bits(wv);
      pk[k][cl] = ((u64)((hb << 16) | hb) << 32) | ((u64)((uint)row << 8));
    }
  }
  __syncthreads();

  const int wave  = tid >> 6;
  const int khalf = wave >> 2;
  const int lane  = tid & 63;
  const int g     = lane >> 4;
  const int b8    = lane & 15;
  const int cl    = (wave & 3) * 4 + g;

  const char* xb = (const char*)xTh;
  const uint  bo = (uint)b8 * 16;
  const int   kb = khalf * 32;

  h2 a0 = (h2)0.0f, a1 = (h2)0.0f, a2 = (h2)0.0f, a3 = (h2)0.0f;
#pragma unroll
  for (int kk = 0; kk < 32; ++kk) {
    const u64  e   = pk[kb + kk][cl];
    const uint off = (uint)e + bo;
    const h2   wh  = __builtin_bit_cast(h2, (uint)(e >> 32));
    const uint4 u  = *(const uint4*)(xb + off);
    a0 += __builtin_bit_cast(h2, u.x) * wh;
    a1 += __builtin_bit_cast(h2, u.y) * wh;
    a2 += __builtin_bit_cast(h2, u.z) * wh;
    a3 += __builtin_bit_cast(h2, u.w) * wh;
  }

  {
    float* r = &res[khalf][cl][b8 * 8];
    r[0] = (float)a0.x; r[1] = (float)a0.y;
    r[2] = (float)a1.x; r[3] = (float)a1.y;
    r[4] = (float)a2.x; r[5] = (float)a2.y;
    r[6] = (float)a3.x; r[7] = (float)a3.y;
  }
  __syncthreads();

  for (int e = tid; e < BATCH * 16; e += 512) {
    const int b = e >> 4, cc = e & 15;
    out[b * COLS + c0 + cc] = res[0][cc][b] + res[1][cc][b];
  }
}

extern "C" void kernel_launch(void* const* d_in, const int* in_sizes, int n_in,
                              void* d_out, int out_size, void* d_ws, size_t ws_size,
                              hipStream_t stream) {
  const float* x   = (const float*)d_in[0];
  const float* w   = (const float*)d_in[1];
  const int*   idx = (const int*)d_in[2];
  float* out = (float*)d_out;

  char* ws = (char*)d_ws;
  ushort* xTh   = (ushort*)(ws);
  uchar*  keep8 = (uchar*)(ws + (1u << 20));

  void* args[6] = {(void*)&x, (void*)&w, (void*)&idx,
                   (void*)&xTh, (void*)&keep8, (void*)&out};
  hipError_t err = hipLaunchCooperativeKernel(
      (const void*)fused_kernel, dim3(512), dim3(512), args, 0, stream);

  if (err != hipSuccess) {
    // Fallback: known-good two-kernel path (round 6).
    ushort* keep16 = (ushort*)keep8;
    u64*    keep   = (u64*)keep8;
    hipLaunchKernelGGL(prep_kernel, dim3(512 + COLS / 64), dim3(256), 0,
                       stream, x, idx, xTh, keep16);
    hipLaunchKernelGGL(branch_main_kernel, dim3(COLS / 16), dim3(512), 0,
                       stream, w, idx, keep, xTh, out);
  }
}

// Round 9
// 26.191 us; speedup vs baseline: 6.6241x; 6.6241x over previous
//
#include <hip/hip_runtime.h>

#define N_IN   4096
#define N_NPB  64
#define COLS   16384
#define BATCH  128

typedef unsigned int       uint;
typedef unsigned short     ushort;
typedef __attribute__((ext_vector_type(2))) _Float16 h2;

// ---------------------------------------------------------------------------
// ws layout:
//   [0,      1 MiB)  xT16 : f16, slice-major [16 slices][4096 rows][8 batches]
//   [1 MiB,  5 MiB)  pku  : uint [64 k][16384 c] = (row << 16) | f16bits(w_eff)
// ---------------------------------------------------------------------------

static __device__ __forceinline__ ushort f16bits(float v) {
  return __builtin_bit_cast(ushort, (_Float16)v);
}

// keepmask + pk-pack for k-group [KB, KB+16): bit = keep iff no later k'
// duplicates idx. Writes pku entries for its 16 k's directly.
template <int KB>
static __device__ __forceinline__ void keep_pk(
    const int* __restrict__ ip, const float* __restrict__ wp,
    uint* __restrict__ pkout) {
  int  g[16];
  uint m[16];
#pragma unroll
  for (int j = 0; j < 16; ++j) { g[j] = ip[(KB + j) * COLS]; m[j] = 0xffffffffu; }
#pragma unroll
  for (int j = 0; j < 16; ++j)
#pragma unroll
    for (int kp = j + 1; kp < 16; ++kp)
      m[j] = min(m[j], (uint)(g[j] ^ g[kp]));
#pragma unroll 4
  for (int kp = KB + 16; kp < 64; ++kp) {
    const int vk = ip[kp * COLS];
#pragma unroll
    for (int j = 0; j < 16; ++j) m[j] = min(m[j], (uint)(g[j] ^ vk));
  }
#pragma unroll
  for (int j = 0; j < 16; ++j) {
    const float wv = (m[j] != 0u) ? wp[(KB + j) * COLS] : 0.0f;
    pkout[(KB + j) * COLS] = ((uint)g[j] << 16) | (uint)f16bits(wv);
  }
}

// Fused prep: blocks [0,512) transpose x -> slice-major f16 xT16;
// blocks [512,768) keepmask + pku pack.
__global__ __launch_bounds__(256, 4) void prep_kernel(
    const float* __restrict__ x, const int* __restrict__ idx,
    const float* __restrict__ w, ushort* __restrict__ xT16,
    uint* __restrict__ pku) {
  const int bid = blockIdx.x;
  const int tid = threadIdx.x;
  if (bid < 512) {
    __shared__ float tile[32][33];
    const int i0 = (bid & 127) * 32;
    const int b0 = (bid >> 7) * 32;
    const int tx = tid & 31;
    const int ty = tid >> 5;    // 0..7
#pragma unroll
    for (int j = 0; j < 32; j += 8)
      tile[ty + j][tx] = x[(b0 + ty + j) * N_IN + i0 + tx];
    __syncthreads();
#pragma unroll
    for (int j = 0; j < 32; j += 8) {
      const int b = b0 + tx, i = i0 + ty + j;
      // xT16[s][i][b&7], s = b>>3 : slice-major so main stages contiguously
      xT16[((b >> 3) << 15) + (i << 3) + (b & 7)] = f16bits(tile[tx][ty + j]);
    }
  } else {
    const int kg = __builtin_amdgcn_readfirstlane(tid >> 6);  // wave-uniform
    const int c  = (bid - 512) * 64 + (tid & 63);
    if      (kg == 0) keep_pk<0 >(idx + c, w + c, pku + c);
    else if (kg == 1) keep_pk<16>(idx + c, w + c, pku + c);
    else if (kg == 2) keep_pk<32>(idx + c, w + c, pku + c);
    else              keep_pk<48>(idx + c, w + c, pku + c);
  }
}

// ---------------------------------------------------------------------------
// Main: out[b,c] = sum_k w_eff[k,c] * x[b, row(k,c)], gathered from LDS.
// Grid 512: bid -> col-range r = bid & 31 (512 cols), slice s = bid >> 5
// (8 batches). XCD pinning: blocks of col-range r all have bid%8 == r%8, so
// pku lines for r stay in one XCD's L2 across its 16 slice-blocks.
// Block: stage xT16[s] (64 KB) into LDS; lane owns one column with its 64
// pk entries in VGPRs; k-loop = ds_read_b128 (16 B = all 8 batches of a row)
// + 4 v_pk_fma_f16. 2 blocks/CU (64 KB LDS each).
// ---------------------------------------------------------------------------
__global__ __launch_bounds__(512, 4) void gather_kernel(
    const uint* __restrict__ pku, const ushort* __restrict__ xT16,
    float* __restrict__ out) {
  __shared__ __align__(16) ushort xls[4096 * 8];   // 64 KB: [row][8 batches]

  const int tid  = threadIdx.x;
  const int bid  = blockIdx.x;
  const int r    = bid & 31;
  const int s    = bid >> 5;
  const int wave = tid >> 6;
  const int lane = tid & 63;
  const int c    = r * 512 + wave * 64 + lane;   // this lane's column

  // 1) This lane's 64 packed entries -> VGPRs (coalesced 256 B per instr).
  uint pk[64];
#pragma unroll
  for (int k = 0; k < 64; ++k) pk[k] = pku[k * COLS + c];

  // 2) Stage slice s (4096 rows x 8 batches f16 = 64 KB) via global_load_lds.
  //    Per instr: 64 lanes x 16 B = 1 KB contiguous; 8 instrs per wave.
  {
    const ushort* src = xT16 + (s << 15);
#pragma unroll
    for (int t = 0; t < 8; ++t) {
      const int off = (wave * 8 + t) * 512;        // ushort offset, 1 KB chunks
      __builtin_amdgcn_global_load_lds(
          (const __attribute__((address_space(1))) void*)(src + off + lane * 8),
          (__attribute__((address_space(3))) void*)(xls + off), 16, 0, 0);
    }
  }
  __syncthreads();   // drains vmcnt incl. global_load_lds

  // 3) Gather-accumulate from LDS.
  h2 a0 = (h2)0.0f, a1 = (h2)0.0f, a2 = (h2)0.0f, a3 = (h2)0.0f;
  const char* xb = (const char*)xls;
#pragma unroll
  for (int k = 0; k < 64; ++k) {
    const uint e   = pk[k];
    const uint off = (e >> 16) << 4;               // row * 16 B
    const uint wb  = e & 0xffffu;
    const h2   wh  = __builtin_bit_cast(h2, (wb << 16) | wb);
    const uint4 u  = *(const uint4*)(xb + off);    // ds_read_b128: 8 batches
    a0 += __builtin_bit_cast(h2, u.x) * wh;        // v_pk_fma_f16
    a1 += __builtin_bit_cast(h2, u.y) * wh;
    a2 += __builtin_bit_cast(h2, u.z) * wh;
    a3 += __builtin_bit_cast(h2, u.w) * wh;
  }

  // 4) Direct coalesced stores: fixed b -> 64 consecutive cols per wave.
  float o[8] = {(float)a0.x, (float)a0.y, (float)a1.x, (float)a1.y,
                (float)a2.x, (float)a2.y, (float)a3.x, (float)a3.y};
#pragma unroll
  for (int b = 0; b < 8; ++b)
    out[(s * 8 + b) * COLS + c] = o[b];
}

extern "C" void kernel_launch(void* const* d_in, const int* in_sizes, int n_in,
                              void* d_out, int out_size, void* d_ws, size_t ws_size,
                              hipStream_t stream) {
  const float* x   = (const float*)d_in[0];
  const float* w   = (const float*)d_in[1];
  const int*   idx = (const int*)d_in[2];
  float* out = (float*)d_out;

  char* ws = (char*)d_ws;
  ushort* xT16 = (ushort*)(ws);
  uint*   pku  = (uint*)(ws + (1u << 20));

  hipLaunchKernelGGL(prep_kernel, dim3(768), dim3(256), 0, stream,
                     x, idx, w, xT16, pku);
  hipLaunchKernelGGL(gather_kernel, dim3(512), dim3(512), 0, stream,
                     pku, xT16, out);
}